// Round 1
// baseline (1516.582 us; speedup 1.0000x reference)
//
#include <hip/hip_runtime.h>
#include <hip/hip_bf16.h>

// Meta3D (LeViT-ish) block: LN1 -> QKV -> attn(+rel-pos bias) -> proj(+ls1 resid)
//                           LN2 -> FC1+GELU -> FC2(+ls2 resid)
// B=1024 imgs, N=49 tok, C=448. All GEMMs are y = x @ W.T with W [out,in] row-major
// => NT GEMM, both A and B fragments load 8 contiguous k (16B) -> MFMA 16x16x32 bf16.

#define NTOK 49
#define CDIM 448
#define NHEAD 8
#define KD 32
#define DV 128
#define DHID 1024
#define HQKV 1536
#define FHID 1792
#define QK_SCALE 0.1767766952966369f

typedef __attribute__((ext_vector_type(8))) short bf16x8;
typedef __attribute__((ext_vector_type(4))) float f32x4;

__device__ __forceinline__ short f2b(float f) {
    __hip_bfloat16 h = __float2bfloat16(f);
    return *reinterpret_cast<short*>(&h);
}
__device__ __forceinline__ float b2f(short s) {
    __hip_bfloat16 h = *reinterpret_cast<__hip_bfloat16*>(&s);
    return __bfloat162float(h);
}

// ---------------- weight fp32 -> bf16 conversion (once per launch) ----------------
__global__ __launch_bounds__(256) void convert_w(
    const float* __restrict__ s0, const float* __restrict__ s1,
    const float* __restrict__ s2, const float* __restrict__ s3,
    short* __restrict__ d0, short* __restrict__ d1,
    short* __restrict__ d2, short* __restrict__ d3)
{
    int i = blockIdx.x * 256 + threadIdx.x;
    if (i < 688128) d0[i] = f2b(s0[i]);        // qkv_w 1536x448
    if (i < 458752) d1[i] = f2b(s1[i]);        // proj_w 448x1024
    if (i < 802816) { d2[i] = f2b(s2[i]);      // fc1_w 1792x448
                      d3[i] = f2b(s3[i]); }    // fc2_w 448x1792
}

// ---------------- LayerNorm: fp32 in -> bf16 out, one wave per 448-row ----------------
__global__ __launch_bounds__(256) void ln_kernel(
    const float* __restrict__ x, short* __restrict__ out,
    const float* __restrict__ g, const float* __restrict__ b)
{
    int row = blockIdx.x * 4 + (threadIdx.x >> 6);
    int lane = threadIdx.x & 63;
    const float* xr = x + (size_t)row * CDIM;
    float v[7];
    float s = 0.f;
#pragma unroll
    for (int i = 0; i < 7; i++) { v[i] = xr[i * 64 + lane]; s += v[i]; }
#pragma unroll
    for (int o = 32; o > 0; o >>= 1) s += __shfl_xor(s, o, 64);
    float mean = s * (1.0f / 448.0f);
    float q = 0.f;
#pragma unroll
    for (int i = 0; i < 7; i++) { float d = v[i] - mean; q += d * d; }
#pragma unroll
    for (int o = 32; o > 0; o >>= 1) q += __shfl_xor(q, o, 64);
    float rstd = rsqrtf(q * (1.0f / 448.0f) + 1e-5f);
    short* orow = out + (size_t)row * CDIM;
#pragma unroll
    for (int i = 0; i < 7; i++) {
        int c = i * 64 + lane;
        orow[c] = f2b((v[i] - mean) * rstd * g[c] + b[c]);
    }
}

// ---------------- bf16 NT GEMM, 128x64 tile, BK=32, fused epilogues ----------------
// EPI 0: out_bf16 = acc + bias[col]
// EPI 1: out_bf16 = gelu_exact(acc + bias[col])
// EPI 2: out_f32  = resid[row,col] + (acc + bias[col]) * ls[col]
template <int EPI>
__global__ __launch_bounds__(256) void gemm_bt(
    const short* __restrict__ A,     // [M,K] bf16
    const short* __restrict__ W,     // [N,K] bf16
    const float* __restrict__ bias,  // [N]
    const float* __restrict__ ls,    // [N]   (EPI 2)
    const float* __restrict__ resid, // [M,N] (EPI 2)
    float* __restrict__ outF,        // (EPI 2)
    short* __restrict__ outB,        // (EPI 0/1)
    int M, int N, int K)
{
    __shared__ short sA[128 * 40];   // +8 pad: 16B-aligned rows, 2-way-max banks
    __shared__ short sB[64 * 40];
    const int tid = threadIdx.x;
    const int m0 = blockIdx.y * 128;
    const int n0 = blockIdx.x * 64;
    const int lane = tid & 63;
    const int w = tid >> 6;
    const int wm = (w & 1) * 64;     // wave M-offset in tile
    const int wn = (w >> 1) * 32;    // wave N-offset in tile
    const int lr = lane & 15;
    const int lq = lane >> 4;

    const f32x4 fzero = {0.f, 0.f, 0.f, 0.f};
    f32x4 acc[4][2];
#pragma unroll
    for (int i = 0; i < 4; i++)
#pragma unroll
        for (int j = 0; j < 2; j++) acc[i][j] = fzero;

    for (int k0 = 0; k0 < K; k0 += 32) {
        // stage A tile: 128 rows x 32 k = 512 x (8 bf16 / 16B); 2 chunks/thread
        for (int c = tid; c < 512; c += 256) {
            int row = c >> 2, kk = (c & 3) << 3;
            *(uint4*)&sA[row * 40 + kk] =
                *(const uint4*)&A[(size_t)(m0 + row) * K + k0 + kk];
        }
        { // stage B tile: 64 rows x 32 k = 256 chunks; 1 chunk/thread
            int row = tid >> 2, kk = (tid & 3) << 3;
            *(uint4*)&sB[row * 40 + kk] =
                *(const uint4*)&W[(size_t)(n0 + row) * K + k0 + kk];
        }
        __syncthreads();
        bf16x8 af[4], bfr[2];
#pragma unroll
        for (int i = 0; i < 4; i++)
            af[i] = *(const bf16x8*)&sA[(wm + i * 16 + lr) * 40 + lq * 8];
#pragma unroll
        for (int j = 0; j < 2; j++)
            bfr[j] = *(const bf16x8*)&sB[(wn + j * 16 + lr) * 40 + lq * 8];
#pragma unroll
        for (int i = 0; i < 4; i++)
#pragma unroll
            for (int j = 0; j < 2; j++)
                acc[i][j] = __builtin_amdgcn_mfma_f32_16x16x32_bf16(
                    af[i], bfr[j], acc[i][j], 0, 0, 0);
        __syncthreads();
    }

    // epilogue: C/D layout col=lane&15, row=(lane>>4)*4+reg  [verified m89/m91]
#pragma unroll
    for (int i = 0; i < 4; i++) {
#pragma unroll
        for (int j = 0; j < 2; j++) {
#pragma unroll
            for (int r = 0; r < 4; r++) {
                int row = m0 + wm + i * 16 + lq * 4 + r;
                int col = n0 + wn + j * 16 + lr;
                float v = acc[i][j][r] + bias[col];
                if (EPI == 0) {
                    outB[(size_t)row * N + col] = f2b(v);
                } else if (EPI == 1) {
                    float gl = 0.5f * v * (1.0f + erff(v * 0.7071067811865475f));
                    outB[(size_t)row * N + col] = f2b(gl);
                } else {
                    outF[(size_t)row * N + col] =
                        resid[(size_t)row * N + col] + v * ls[col];
                }
            }
        }
    }
}

// ---------------- attention: one block per (image, head) ----------------
__global__ __launch_bounds__(256) void attn_kernel(
    const short* __restrict__ qkv,    // [R,1536] bf16; per-head 192 = q32|k32|v128
    const float* __restrict__ biases, // [8,49]
    const int* __restrict__ bias_idx, // [49,49] values 0..48
    short* __restrict__ attn_out)     // [R,1024] bf16
{
    __shared__ float sq[49][33];
    __shared__ float sk[49][33];
    __shared__ float sv[49][128];
    __shared__ float sc[49 * 49];
    const int head = blockIdx.x;
    const size_t imgrow = (size_t)blockIdx.y * NTOK;
    const int tid = threadIdx.x;

    for (int t = tid; t < NTOK * 192; t += 256) {
        int n = t / 192, c = t % 192;
        float v = b2f(qkv[(imgrow + n) * HQKV + head * 192 + c]);
        if (c < 32) sq[n][c] = v * QK_SCALE;
        else if (c < 64) sk[n][c - 32] = v;
        else sv[n][c - 64] = v;
    }
    __syncthreads();

    for (int p = tid; p < NTOK * NTOK; p += 256) {
        int n = p / NTOK, m = p % NTOK;
        float s = 0.f;
#pragma unroll
        for (int d = 0; d < 32; d++) s += sq[n][d] * sk[m][d];
        sc[p] = s + biases[head * 49 + bias_idx[p]];
    }
    __syncthreads();

    if (tid < NTOK) {  // per-row softmax, thread = row
        float mx = -1e30f;
        for (int m = 0; m < NTOK; m++) mx = fmaxf(mx, sc[tid * NTOK + m]);
        float ssum = 0.f;
        for (int m = 0; m < NTOK; m++) {
            float e = __expf(sc[tid * NTOK + m] - mx);
            sc[tid * NTOK + m] = e;
            ssum += e;
        }
        float inv = 1.0f / ssum;
        for (int m = 0; m < NTOK; m++) sc[tid * NTOK + m] *= inv;
    }
    __syncthreads();

    for (int p = tid; p < NTOK * DV; p += 256) {
        int n = p >> 7, d = p & 127;
        float s = 0.f;
        for (int m = 0; m < NTOK; m++) s += sc[n * NTOK + m] * sv[m][d];
        attn_out[(imgrow + n) * DHID + head * DV + d] = f2b(s);
    }
}

extern "C" void kernel_launch(void* const* d_in, const int* in_sizes, int n_in,
                              void* d_out, int out_size, void* d_ws, size_t ws_size,
                              hipStream_t stream) {
    const float* x      = (const float*)d_in[0];
    const float* qkv_w  = (const float*)d_in[1];
    const float* qkv_b  = (const float*)d_in[2];
    const float* proj_w = (const float*)d_in[3];
    const float* proj_b = (const float*)d_in[4];
    const float* fc1_w  = (const float*)d_in[5];
    const float* fc1_b  = (const float*)d_in[6];
    const float* fc2_w  = (const float*)d_in[7];
    const float* fc2_b  = (const float*)d_in[8];
    const float* n1g    = (const float*)d_in[9];
    const float* n1b    = (const float*)d_in[10];
    const float* n2g    = (const float*)d_in[11];
    const float* n2b    = (const float*)d_in[12];
    const float* ls1    = (const float*)d_in[13];
    const float* ls2    = (const float*)d_in[14];
    const float* biases = (const float*)d_in[15];
    const int*   bidx   = (const int*)d_in[16];
    float* outp = (float*)d_out;

    char* ws = (char*)d_ws;
    short* Wq = (short*)ws; ws += (size_t)688128 * 2;
    short* Wp = (short*)ws; ws += (size_t)458752 * 2;
    short* W1 = (short*)ws; ws += (size_t)802816 * 2;
    short* W2 = (short*)ws; ws += (size_t)802816 * 2;
    const size_t fixed = 5505024;

    // pick images/chunk so scratch fits: per-row bytes = h(896)+x1(1792)+qkv(3072)+attn(2048)
    int IC = 1024;
    while (IC > 128) {
        size_t Rr = (size_t)IC * NTOK;
        if (fixed + Rr * 7808ull <= ws_size) break;
        IC >>= 1;
    }
    const size_t R = (size_t)IC * NTOK;
    short* hbuf = (short*)ws; ws += R * CDIM * 2;   // LN out (reused for LN2 out)
    float* x1   = (float*)ws; ws += R * CDIM * 4;   // post-attn residual (fp32)
    short* qkvb = (short*)ws; ws += R * HQKV * 2;   // qkv
    short* attb = (short*)ws; ws += R * DHID * 2;   // attention out
    short* gbuf = qkvb;  // FC1 out [R,1792] overlays qkv+attn (both dead by then)

    convert_w<<<3136, 256, 0, stream>>>(qkv_w, proj_w, fc1_w, fc2_w, Wq, Wp, W1, W2);

    for (int c0 = 0; c0 < 1024; c0 += IC) {
        const float* xc = x + (size_t)c0 * NTOK * CDIM;
        float* oc = outp + (size_t)c0 * NTOK * CDIM;
        const int Ri = IC * NTOK;

        ln_kernel<<<Ri / 4, 256, 0, stream>>>(xc, hbuf, n1g, n1b);
        gemm_bt<0><<<dim3(HQKV / 64, Ri / 128), 256, 0, stream>>>(
            hbuf, Wq, qkv_b, nullptr, nullptr, nullptr, qkvb, Ri, HQKV, CDIM);
        attn_kernel<<<dim3(NHEAD, IC), 256, 0, stream>>>(qkvb, biases, bidx, attb);
        gemm_bt<2><<<dim3(CDIM / 64, Ri / 128), 256, 0, stream>>>(
            attb, Wp, proj_b, ls1, xc, x1, nullptr, Ri, CDIM, DHID);
        ln_kernel<<<Ri / 4, 256, 0, stream>>>(x1, hbuf, n2g, n2b);
        gemm_bt<1><<<dim3(FHID / 64, Ri / 128), 256, 0, stream>>>(
            hbuf, W1, fc1_b, nullptr, nullptr, nullptr, gbuf, Ri, FHID, CDIM);
        gemm_bt<2><<<dim3(CDIM / 64, Ri / 128), 256, 0, stream>>>(
            gbuf, W2, fc2_b, ls2, x1, oc, nullptr, Ri, CDIM, FHID);
    }
}

// Round 2
// 1403.515 us; speedup vs baseline: 1.0806x; 1.0806x over previous
//
#include <hip/hip_runtime.h>
#include <hip/hip_bf16.h>

// Meta3D block: LN1 -> QKV -> MFMA-attn(+rel-pos bias) -> proj(+ls1 resid)
//               LN2 -> FC1+GELU -> FC2(+ls2 resid)
// B=1024 imgs, N=49 tok, C=448. GEMMs are y = x @ W.T (NT), bf16 MFMA 16x16x32.

#define NTOK 49
#define CDIM 448
#define NHEAD 8
#define DHID 1024
#define HQKV 1536
#define FHID 1792
#define QK_SCALE 0.1767766952966369f
#define INV_SCALE 5.656854249492381f

typedef __attribute__((ext_vector_type(8))) short bf16x8;
typedef __attribute__((ext_vector_type(4))) float f32x4;
typedef unsigned int u32;

__device__ __forceinline__ short f2b(float f) {
    __hip_bfloat16 h = __float2bfloat16(f);
    return *reinterpret_cast<short*>(&h);
}

// async global->LDS, 16B per lane; LDS dest = wave-uniform base + lane*16
__device__ __forceinline__ void gll16(const short* g, short* l) {
    __builtin_amdgcn_global_load_lds(
        (const __attribute__((address_space(1))) u32*)g,
        (__attribute__((address_space(3))) u32*)l, 16, 0, 0);
}

// ---------------- weight fp32 -> bf16 (once per launch) ----------------
__global__ __launch_bounds__(256) void convert_w(
    const float* __restrict__ s0, const float* __restrict__ s1,
    const float* __restrict__ s2, const float* __restrict__ s3,
    short* __restrict__ d0, short* __restrict__ d1,
    short* __restrict__ d2, short* __restrict__ d3)
{
    int i = blockIdx.x * 256 + threadIdx.x;
    if (i < 688128) d0[i] = f2b(s0[i]);        // qkv_w 1536x448
    if (i < 458752) d1[i] = f2b(s1[i]);        // proj_w 448x1024
    if (i < 802816) { d2[i] = f2b(s2[i]);      // fc1_w 1792x448
                      d3[i] = f2b(s3[i]); }    // fc2_w 448x1792
}

// ---------------- expand rel-pos bias to full [8,49,49] fp32 ----------------
__global__ __launch_bounds__(256) void build_bias(
    const float* __restrict__ biases, const int* __restrict__ bidx,
    float* __restrict__ bfull)
{
    int i = blockIdx.x * 256 + threadIdx.x;
    if (i < NHEAD * NTOK * NTOK) {
        int h = i / (NTOK * NTOK), p = i % (NTOK * NTOK);
        bfull[i] = biases[h * NTOK + bidx[p]];
    }
}

// ---------------- LayerNorm: fp32 -> bf16, one wave per 448-row ----------------
__global__ __launch_bounds__(256) void ln_kernel(
    const float* __restrict__ x, short* __restrict__ out,
    const float* __restrict__ g, const float* __restrict__ b)
{
    int row = blockIdx.x * 4 + (threadIdx.x >> 6);
    int lane = threadIdx.x & 63;
    const float* xr = x + (size_t)row * CDIM;
    float v[7];
    float s = 0.f;
#pragma unroll
    for (int i = 0; i < 7; i++) { v[i] = xr[i * 64 + lane]; s += v[i]; }
#pragma unroll
    for (int o = 32; o > 0; o >>= 1) s += __shfl_xor(s, o, 64);
    float mean = s * (1.0f / 448.0f);
    float q = 0.f;
#pragma unroll
    for (int i = 0; i < 7; i++) { float d = v[i] - mean; q += d * d; }
#pragma unroll
    for (int o = 32; o > 0; o >>= 1) q += __shfl_xor(q, o, 64);
    float rstd = rsqrtf(q * (1.0f / 448.0f) + 1e-5f);
    short* orow = out + (size_t)row * CDIM;
#pragma unroll
    for (int i = 0; i < 7; i++) {
        int c = i * 64 + lane;
        orow[c] = f2b((v[i] - mean) * rstd * g[c] + b[c]);
    }
}

// ---------------- bf16 NT GEMM, 128x128 tile, BK=32, global_load_lds ----------------
// LDS layout: 8 panels of (16 rows x 32 k), panel stored k-quad-major:
// chunk c (16B) = panel p=c>>6, kq=(c>>4)&3, row_in=c&15 -> both DMA dest and
// frag reads are base + lane*16 (conflict-free, no padding needed).
// EPI 0: out_bf16 = acc + bias[col]
// EPI 1: out_bf16 = gelu_exact(acc + bias[col])
// EPI 2: out_f32  = resid[row,col] + (acc + bias[col]) * ls[col]
template <int EPI>
__global__ __launch_bounds__(256) void gemm_bt(
    const short* __restrict__ A,     // [M,K] bf16
    const short* __restrict__ W,     // [N,K] bf16 (rows clamped if N%128)
    const float* __restrict__ bias,  // [N]
    const float* __restrict__ ls,    // [N]   (EPI 2)
    const float* __restrict__ resid, // [M,N] (EPI 2)
    float* __restrict__ outF,        // (EPI 2)
    short* __restrict__ outB,        // (EPI 0/1)
    int M, int N, int K)
{
    __shared__ short sA[4096];   // 128x32 bf16 = 8KB
    __shared__ short sB[4096];
    const int tid = threadIdx.x;
    const int lane = tid & 63;
    const int w = tid >> 6;
    const int lr = lane & 15, lq = lane >> 4;
    const int m0 = blockIdx.y * 128;
    const int n0 = blockIdx.x * 128;

    // wave w stages panels {2w, 2w+1} of both tiles; lane chunk = iter*64+lane
    // -> row = iter*16 + lr, k-offset = lq*8
    const int it0 = 2 * w, it1 = 2 * w + 1;
    const short* pA0 = A + (size_t)(m0 + it0 * 16 + lr) * K + lq * 8;
    const short* pA1 = A + (size_t)(m0 + it1 * 16 + lr) * K + lq * 8;
    int rB0 = n0 + it0 * 16 + lr; rB0 = rB0 < N ? rB0 : N - 1;
    int rB1 = n0 + it1 * 16 + lr; rB1 = rB1 < N ? rB1 : N - 1;
    const short* pB0 = W + (size_t)rB0 * K + lq * 8;
    const short* pB1 = W + (size_t)rB1 * K + lq * 8;
    short* lA0 = sA + it0 * 512;
    short* lA1 = sA + it1 * 512;
    short* lB0 = sB + it0 * 512;
    short* lB1 = sB + it1 * 512;

    const f32x4 fz = {0.f, 0.f, 0.f, 0.f};
    f32x4 acc[4][4];
#pragma unroll
    for (int i = 0; i < 4; i++)
#pragma unroll
        for (int j = 0; j < 4; j++) acc[i][j] = fz;

    const char* baseA = (const char*)sA + (w & 1) * 4096 + lane * 16;
    const char* baseB = (const char*)sB + (w >> 1) * 4096 + lane * 16;

    for (int k0 = 0; k0 < K; k0 += 32) {
        gll16(pA0, lA0); gll16(pA1, lA1);
        gll16(pB0, lB0); gll16(pB1, lB1);
        pA0 += 32; pA1 += 32; pB0 += 32; pB1 += 32;
        __syncthreads();   // drains vmcnt: DMA complete
        bf16x8 af[4], bfb[4];
#pragma unroll
        for (int i = 0; i < 4; i++) af[i] = *(const bf16x8*)(baseA + i * 1024);
#pragma unroll
        for (int j = 0; j < 4; j++) bfb[j] = *(const bf16x8*)(baseB + j * 1024);
#pragma unroll
        for (int i = 0; i < 4; i++)
#pragma unroll
            for (int j = 0; j < 4; j++)
                acc[i][j] = __builtin_amdgcn_mfma_f32_16x16x32_bf16(
                    af[i], bfb[j], acc[i][j], 0, 0, 0);
        __syncthreads();
    }

    const int wm = (w & 1) * 64, wn = (w >> 1) * 64;
    // C/D layout: col=lane&15, row=(lane>>4)*4+reg  [verified m89/m91]
#pragma unroll
    for (int i = 0; i < 4; i++)
#pragma unroll
        for (int j = 0; j < 4; j++)
#pragma unroll
            for (int r = 0; r < 4; r++) {
                int row = m0 + wm + i * 16 + lq * 4 + r;
                int col = n0 + wn + j * 16 + lr;
                if (col < N) {
                    float v = acc[i][j][r] + bias[col];
                    if (EPI == 0) {
                        outB[(size_t)row * N + col] = f2b(v);
                    } else if (EPI == 1) {
                        float gl = 0.5f * v * (1.0f + erff(v * 0.7071067811865475f));
                        outB[(size_t)row * N + col] = f2b(gl);
                    } else {
                        outF[(size_t)row * N + col] =
                            resid[(size_t)row * N + col] + v * ls[col];
                    }
                }
            }
}

// ---------------- MFMA attention: 1 wave per (image, head) ----------------
__global__ __launch_bounds__(64) void attn_mfma(
    const short* __restrict__ qkv,    // [R,1536]; per-head 192 = q32|k32|v128
    const float* __restrict__ bfull,  // [8,49,49] fp32
    short* __restrict__ attn_out)     // [R,1024]
{
    __shared__ short sP[64 * 72];     // P bf16, row stride 144B (16B aligned)
    __shared__ short sVt[128 * 72];   // V^T bf16 [d][tok(0..63)]
    const int head = blockIdx.x;
    const size_t base = (size_t)blockIdx.y * NTOK;
    const int lane = threadIdx.x;
    const int lr = lane & 15, lq = lane >> 4;

    // C-init = bias/SCALE; mask cols>=49 with -1e30 (survives MFMA add + *SCALE)
    f32x4 sc[4][4];
#pragma unroll
    for (int i = 0; i < 4; i++)
#pragma unroll
        for (int j = 0; j < 4; j++)
#pragma unroll
            for (int r = 0; r < 4; r++) {
                int row = i * 16 + lq * 4 + r, col = j * 16 + lr;
                float v;
                if (col >= NTOK)      v = -1e30f;
                else if (row < NTOK)  v = bfull[head * (NTOK * NTOK) + row * NTOK + col] * INV_SCALE;
                else                  v = 0.f;
                sc[i][j][r] = v;
            }

    // Q/K fragments straight from global (k-contiguous 16B; rows clamped)
    bf16x8 qf[4], kf[4];
#pragma unroll
    for (int i = 0; i < 4; i++) {
        int r = i * 16 + lr; r = r < NTOK ? r : NTOK - 1;
        const short* rp = qkv + (base + r) * HQKV + head * 192;
        qf[i] = *(const bf16x8*)(rp + lq * 8);
        kf[i] = *(const bf16x8*)(rp + 32 + lq * 8);
    }
#pragma unroll
    for (int i = 0; i < 4; i++)
#pragma unroll
        for (int j = 0; j < 4; j++)
            sc[i][j] = __builtin_amdgcn_mfma_f32_16x16x32_bf16(
                qf[i], kf[j], sc[i][j], 0, 0, 0);

    // stage V^T: [d][tok], zero-pad toks 49..63 (P there is exactly 0, avoid Inf*0)
    for (int e = lane; e < NTOK * 128; e += 64) {
        int tok = e >> 7, d = e & 127;
        sVt[d * 72 + tok] = qkv[(base + tok) * HQKV + head * 192 + 64 + d];
    }
    for (int t = lane; t < 128 * 15; t += 64) {
        int d = t / 15, tok = NTOK + t % 15;
        sVt[d * 72 + tok] = 0;
    }

    // softmax over (j regs x 16 lanes) per output row; P -> sP as bf16
#pragma unroll
    for (int i = 0; i < 4; i++)
#pragma unroll
        for (int r = 0; r < 4; r++) {
            float s0 = sc[i][0][r] * QK_SCALE;
            float s1 = sc[i][1][r] * QK_SCALE;
            float s2 = sc[i][2][r] * QK_SCALE;
            float s3 = sc[i][3][r] * QK_SCALE;
            float m = fmaxf(fmaxf(s0, s1), fmaxf(s2, s3));
#pragma unroll
            for (int o = 1; o < 16; o <<= 1) m = fmaxf(m, __shfl_xor(m, o, 64));
            float e0 = __expf(s0 - m), e1 = __expf(s1 - m);
            float e2 = __expf(s2 - m), e3 = __expf(s3 - m);
            float l = e0 + e1 + e2 + e3;
#pragma unroll
            for (int o = 1; o < 16; o <<= 1) l += __shfl_xor(l, o, 64);
            float inv = 1.0f / l;
            short* pr = &sP[(i * 16 + lq * 4 + r) * 72];
            pr[lr]      = f2b(e0 * inv);
            pr[16 + lr] = f2b(e1 * inv);
            pr[32 + lr] = f2b(e2 * inv);
            pr[48 + lr] = f2b(e3 * inv);
        }
    __syncthreads();

    // PV: A = P (rows=query, k=token), B = V^T rows (n=d, k=token); 2 d-halves
    bf16x8 pa[4][2];
#pragma unroll
    for (int i = 0; i < 4; i++)
#pragma unroll
        for (int kk = 0; kk < 2; kk++)
            pa[i][kk] = *(const bf16x8*)&sP[(i * 16 + lr) * 72 + kk * 32 + lq * 8];

#pragma unroll
    for (int half = 0; half < 2; half++) {
        const f32x4 fz = {0.f, 0.f, 0.f, 0.f};
        f32x4 o[4][4];
        bf16x8 pb[4][2];
#pragma unroll
        for (int j = 0; j < 4; j++)
#pragma unroll
            for (int kk = 0; kk < 2; kk++)
                pb[j][kk] = *(const bf16x8*)
                    &sVt[(half * 64 + j * 16 + lr) * 72 + kk * 32 + lq * 8];
#pragma unroll
        for (int i = 0; i < 4; i++)
#pragma unroll
            for (int j = 0; j < 4; j++) {
                o[i][j] = __builtin_amdgcn_mfma_f32_16x16x32_bf16(
                    pa[i][0], pb[j][0], fz, 0, 0, 0);
                o[i][j] = __builtin_amdgcn_mfma_f32_16x16x32_bf16(
                    pa[i][1], pb[j][1], o[i][j], 0, 0, 0);
            }
#pragma unroll
        for (int i = 0; i < 4; i++)
#pragma unroll
            for (int j = 0; j < 4; j++)
#pragma unroll
                for (int r = 0; r < 4; r++) {
                    int row = i * 16 + lq * 4 + r;
                    if (row < NTOK)
                        attn_out[(base + row) * DHID + head * 128 + half * 64 + j * 16 + lr] =
                            f2b(o[i][j][r]);
                }
    }
}

extern "C" void kernel_launch(void* const* d_in, const int* in_sizes, int n_in,
                              void* d_out, int out_size, void* d_ws, size_t ws_size,
                              hipStream_t stream) {
    const float* x      = (const float*)d_in[0];
    const float* qkv_w  = (const float*)d_in[1];
    const float* qkv_b  = (const float*)d_in[2];
    const float* proj_w = (const float*)d_in[3];
    const float* proj_b = (const float*)d_in[4];
    const float* fc1_w  = (const float*)d_in[5];
    const float* fc1_b  = (const float*)d_in[6];
    const float* fc2_w  = (const float*)d_in[7];
    const float* fc2_b  = (const float*)d_in[8];
    const float* n1g    = (const float*)d_in[9];
    const float* n1b    = (const float*)d_in[10];
    const float* n2g    = (const float*)d_in[11];
    const float* n2b    = (const float*)d_in[12];
    const float* ls1    = (const float*)d_in[13];
    const float* ls2    = (const float*)d_in[14];
    const float* biases = (const float*)d_in[15];
    const int*   bidx   = (const int*)d_in[16];
    float* outp = (float*)d_out;

    char* ws = (char*)d_ws;
    short* Wq = (short*)ws; ws += (size_t)688128 * 2;
    short* Wp = (short*)ws; ws += (size_t)458752 * 2;
    short* W1 = (short*)ws; ws += (size_t)802816 * 2;
    short* W2 = (short*)ws; ws += (size_t)802816 * 2;
    float* bfull = (float*)ws; ws += (size_t)NHEAD * NTOK * NTOK * 4;
    const size_t fixed = 5505024 + (size_t)NHEAD * NTOK * NTOK * 4;

    int IC = 1024;
    while (IC > 128) {
        size_t Rr = (size_t)IC * NTOK;
        if (fixed + Rr * 7808ull <= ws_size) break;
        IC >>= 1;
    }
    const size_t R = (size_t)IC * NTOK;
    short* hbuf = (short*)ws; ws += R * CDIM * 2;   // LN out (reused LN2)
    float* x1   = (float*)ws; ws += R * CDIM * 4;   // post-attn residual fp32
    short* qkvb = (short*)ws; ws += R * HQKV * 2;
    short* attb = (short*)ws; ws += R * DHID * 2;
    short* gbuf = qkvb;  // FC1 out [R,1792] overlays qkv+attn (dead by then)

    convert_w<<<3136, 256, 0, stream>>>(qkv_w, proj_w, fc1_w, fc2_w, Wq, Wp, W1, W2);
    build_bias<<<(NHEAD * NTOK * NTOK + 255) / 256, 256, 0, stream>>>(biases, bidx, bfull);

    for (int c0 = 0; c0 < 1024; c0 += IC) {
        const float* xc = x + (size_t)c0 * NTOK * CDIM;
        float* oc = outp + (size_t)c0 * NTOK * CDIM;
        const int Ri = IC * NTOK;

        ln_kernel<<<Ri / 4, 256, 0, stream>>>(xc, hbuf, n1g, n1b);
        gemm_bt<0><<<dim3(HQKV / 128, Ri / 128), 256, 0, stream>>>(
            hbuf, Wq, qkv_b, nullptr, nullptr, nullptr, qkvb, Ri, HQKV, CDIM);
        attn_mfma<<<dim3(NHEAD, IC), 64, 0, stream>>>(qkvb, bfull, attb);
        gemm_bt<2><<<dim3(4, Ri / 128), 256, 0, stream>>>(
            attb, Wp, proj_b, ls1, xc, x1, nullptr, Ri, CDIM, DHID);
        ln_kernel<<<Ri / 4, 256, 0, stream>>>(x1, hbuf, n2g, n2b);
        gemm_bt<1><<<dim3(FHID / 128, Ri / 128), 256, 0, stream>>>(
            hbuf, W1, fc1_b, nullptr, nullptr, nullptr, gbuf, Ri, FHID, CDIM);
        gemm_bt<2><<<dim3(4, Ri / 128), 256, 0, stream>>>(
            gbuf, W2, fc2_b, ls2, x1, oc, nullptr, Ri, CDIM, FHID);
    }
}

// Round 3
// 1378.905 us; speedup vs baseline: 1.0998x; 1.0178x over previous
//
#include <hip/hip_runtime.h>
#include <hip/hip_bf16.h>

// Meta3D block: LN1 -> QKV -> MFMA-attn(+rel-pos bias) -> proj(+ls1 resid)
//               LN2 -> FC1+GELU -> FC2(+ls2 resid)
// B=1024 imgs, N=49 tok, C=448. GEMMs are y = x @ W.T (NT), bf16 MFMA 16x16x32.
// R3: GEMM K-loop double-buffered (prefetch distance 1, ONE barrier/iter) so the
// vmcnt(0) drain at the barrier waits on DMAs issued a full iteration earlier.

#define NTOK 49
#define CDIM 448
#define NHEAD 8
#define DHID 1024
#define HQKV 1536
#define FHID 1792
#define QK_SCALE 0.1767766952966369f
#define INV_SCALE 5.656854249492381f

typedef __attribute__((ext_vector_type(8))) short bf16x8;
typedef __attribute__((ext_vector_type(4))) float f32x4;
typedef unsigned int u32;

__device__ __forceinline__ short f2b(float f) {
    __hip_bfloat16 h = __float2bfloat16(f);
    return *reinterpret_cast<short*>(&h);
}

// async global->LDS, 16B per lane; LDS dest = wave-uniform base + lane*16
__device__ __forceinline__ void gll16(const short* g, short* l) {
    __builtin_amdgcn_global_load_lds(
        (const __attribute__((address_space(1))) u32*)g,
        (__attribute__((address_space(3))) u32*)l, 16, 0, 0);
}

// ---------------- weight fp32 -> bf16 (once per launch) ----------------
__global__ __launch_bounds__(256) void convert_w(
    const float* __restrict__ s0, const float* __restrict__ s1,
    const float* __restrict__ s2, const float* __restrict__ s3,
    short* __restrict__ d0, short* __restrict__ d1,
    short* __restrict__ d2, short* __restrict__ d3)
{
    int i = blockIdx.x * 256 + threadIdx.x;
    if (i < 688128) d0[i] = f2b(s0[i]);        // qkv_w 1536x448
    if (i < 458752) d1[i] = f2b(s1[i]);        // proj_w 448x1024
    if (i < 802816) { d2[i] = f2b(s2[i]);      // fc1_w 1792x448
                      d3[i] = f2b(s3[i]); }    // fc2_w 448x1792
}

// ---------------- expand rel-pos bias to full [8,49,49] fp32 ----------------
__global__ __launch_bounds__(256) void build_bias(
    const float* __restrict__ biases, const int* __restrict__ bidx,
    float* __restrict__ bfull)
{
    int i = blockIdx.x * 256 + threadIdx.x;
    if (i < NHEAD * NTOK * NTOK) {
        int h = i / (NTOK * NTOK), p = i % (NTOK * NTOK);
        bfull[i] = biases[h * NTOK + bidx[p]];
    }
}

// ---------------- LayerNorm: fp32 -> bf16, one wave per 448-row ----------------
__global__ __launch_bounds__(256) void ln_kernel(
    const float* __restrict__ x, short* __restrict__ out,
    const float* __restrict__ g, const float* __restrict__ b)
{
    int row = blockIdx.x * 4 + (threadIdx.x >> 6);
    int lane = threadIdx.x & 63;
    const float* xr = x + (size_t)row * CDIM;
    float v[7];
    float s = 0.f;
#pragma unroll
    for (int i = 0; i < 7; i++) { v[i] = xr[i * 64 + lane]; s += v[i]; }
#pragma unroll
    for (int o = 32; o > 0; o >>= 1) s += __shfl_xor(s, o, 64);
    float mean = s * (1.0f / 448.0f);
    float q = 0.f;
#pragma unroll
    for (int i = 0; i < 7; i++) { float d = v[i] - mean; q += d * d; }
#pragma unroll
    for (int o = 32; o > 0; o >>= 1) q += __shfl_xor(q, o, 64);
    float rstd = rsqrtf(q * (1.0f / 448.0f) + 1e-5f);
    short* orow = out + (size_t)row * CDIM;
#pragma unroll
    for (int i = 0; i < 7; i++) {
        int c = i * 64 + lane;
        orow[c] = f2b((v[i] - mean) * rstd * g[c] + b[c]);
    }
}

// ---------------- bf16 NT GEMM, 128x128 tile, BK=32, dbuf global_load_lds ----------------
// LDS per tile: 8 panels of (16 rows x 32 k), panel k-quad-major -> DMA dest and
// frag reads are both base + lane*16 (conflict-free).
// Pipeline: iter i uses buf i&1; at top-of-iter barrier the only outstanding DMAs
// are the ones issued in iter i-1 (into buf i&1) -> drain is cheap. DMA issued in
// iter i targets buf (i+1)&1, whose readers (iter i-1) all passed the barrier.
// EPI 0: out_bf16 = acc + bias[col]
// EPI 1: out_bf16 = gelu_exact(acc + bias[col])
// EPI 2: out_f32  = resid[row,col] + (acc + bias[col]) * ls[col]
template <int EPI>
__global__ __launch_bounds__(256) void gemm_bt(
    const short* __restrict__ A,     // [M,K] bf16
    const short* __restrict__ W,     // [N,K] bf16 (rows clamped if N%128)
    const float* __restrict__ bias,  // [N]
    const float* __restrict__ ls,    // [N]   (EPI 2)
    const float* __restrict__ resid, // [M,N] (EPI 2)
    float* __restrict__ outF,        // (EPI 2)
    short* __restrict__ outB,        // (EPI 0/1)
    int M, int N, int K)
{
    __shared__ short sA[2][4096];   // 2 x 8KB
    __shared__ short sB[2][4096];
    const int tid = threadIdx.x;
    const int lane = tid & 63;
    const int w = tid >> 6;
    const int lr = lane & 15, lq = lane >> 4;
    const int m0 = blockIdx.y * 128;
    const int n0 = blockIdx.x * 128;

    // wave w stages panels {2w, 2w+1}; lane chunk = iter*64+lane
    // -> row = iter*16 + lr, k-offset = lq*8
    const int it0 = 2 * w, it1 = 2 * w + 1;
    const short* pA0 = A + (size_t)(m0 + it0 * 16 + lr) * K + lq * 8;
    const short* pA1 = A + (size_t)(m0 + it1 * 16 + lr) * K + lq * 8;
    int rB0 = n0 + it0 * 16 + lr; rB0 = rB0 < N ? rB0 : N - 1;
    int rB1 = n0 + it1 * 16 + lr; rB1 = rB1 < N ? rB1 : N - 1;
    const short* pB0 = W + (size_t)rB0 * K + lq * 8;
    const short* pB1 = W + (size_t)rB1 * K + lq * 8;
    const int oA0 = it0 * 512, oA1 = it1 * 512;

    const f32x4 fz = {0.f, 0.f, 0.f, 0.f};
    f32x4 acc[4][4];
#pragma unroll
    for (int i = 0; i < 4; i++)
#pragma unroll
        for (int j = 0; j < 4; j++) acc[i][j] = fz;

    const int rdA = (w & 1) * 4096 + lane * 16;   // byte offset inside buffer
    const int rdB = (w >> 1) * 4096 + lane * 16;

    // prologue: stage tile 0 into buf 0
    gll16(pA0, sA[0] + oA0); gll16(pA1, sA[0] + oA1);
    gll16(pB0, sB[0] + oA0); gll16(pB1, sB[0] + oA1);
    pA0 += 32; pA1 += 32; pB0 += 32; pB1 += 32;

    int buf = 0;
    for (int k0 = 0; k0 < K; k0 += 32) {
        __syncthreads();          // drains DMAs issued one iteration ago
        if (k0 + 32 < K) {        // prefetch next tile into other buffer
            short* dA = sA[buf ^ 1];
            short* dB = sB[buf ^ 1];
            gll16(pA0, dA + oA0); gll16(pA1, dA + oA1);
            gll16(pB0, dB + oA0); gll16(pB1, dB + oA1);
            pA0 += 32; pA1 += 32; pB0 += 32; pB1 += 32;
        }
        const char* baseA = (const char*)sA[buf] + rdA;
        const char* baseB = (const char*)sB[buf] + rdB;
        bf16x8 af[4], bfb[4];
#pragma unroll
        for (int i = 0; i < 4; i++) af[i] = *(const bf16x8*)(baseA + i * 1024);
#pragma unroll
        for (int j = 0; j < 4; j++) bfb[j] = *(const bf16x8*)(baseB + j * 1024);
#pragma unroll
        for (int i = 0; i < 4; i++)
#pragma unroll
            for (int j = 0; j < 4; j++)
                acc[i][j] = __builtin_amdgcn_mfma_f32_16x16x32_bf16(
                    af[i], bfb[j], acc[i][j], 0, 0, 0);
        buf ^= 1;
    }

    const int wm = (w & 1) * 64, wn = (w >> 1) * 64;
    // C/D layout: col=lane&15, row=(lane>>4)*4+reg  [verified m89/m91]
#pragma unroll
    for (int i = 0; i < 4; i++)
#pragma unroll
        for (int j = 0; j < 4; j++)
#pragma unroll
            for (int r = 0; r < 4; r++) {
                int row = m0 + wm + i * 16 + lq * 4 + r;
                int col = n0 + wn + j * 16 + lr;
                if (col < N) {
                    float v = acc[i][j][r] + bias[col];
                    if (EPI == 0) {
                        outB[(size_t)row * N + col] = f2b(v);
                    } else if (EPI == 1) {
                        float gl = 0.5f * v * (1.0f + erff(v * 0.7071067811865475f));
                        outB[(size_t)row * N + col] = f2b(gl);
                    } else {
                        outF[(size_t)row * N + col] =
                            resid[(size_t)row * N + col] + v * ls[col];
                    }
                }
            }
}

// ---------------- MFMA attention: 1 wave per (image, head) ----------------
__global__ __launch_bounds__(64) void attn_mfma(
    const short* __restrict__ qkv,    // [R,1536]; per-head 192 = q32|k32|v128
    const float* __restrict__ bfull,  // [8,49,49] fp32
    short* __restrict__ attn_out)     // [R,1024]
{
    __shared__ short sP[64 * 72];     // P bf16, row stride 144B (16B aligned)
    __shared__ short sVt[128 * 72];   // V^T bf16 [d][tok(0..63)]
    const int head = blockIdx.x;
    const size_t base = (size_t)blockIdx.y * NTOK;
    const int lane = threadIdx.x;
    const int lr = lane & 15, lq = lane >> 4;

    // C-init = bias/SCALE; mask cols>=49 with -1e30 (survives MFMA add + *SCALE)
    f32x4 sc[4][4];
#pragma unroll
    for (int i = 0; i < 4; i++)
#pragma unroll
        for (int j = 0; j < 4; j++)
#pragma unroll
            for (int r = 0; r < 4; r++) {
                int row = i * 16 + lq * 4 + r, col = j * 16 + lr;
                float v;
                if (col >= NTOK)      v = -1e30f;
                else if (row < NTOK)  v = bfull[head * (NTOK * NTOK) + row * NTOK + col] * INV_SCALE;
                else                  v = 0.f;
                sc[i][j][r] = v;
            }

    // Q/K fragments straight from global (k-contiguous 16B; rows clamped)
    bf16x8 qf[4], kf[4];
#pragma unroll
    for (int i = 0; i < 4; i++) {
        int r = i * 16 + lr; r = r < NTOK ? r : NTOK - 1;
        const short* rp = qkv + (base + r) * HQKV + head * 192;
        qf[i] = *(const bf16x8*)(rp + lq * 8);
        kf[i] = *(const bf16x8*)(rp + 32 + lq * 8);
    }
#pragma unroll
    for (int i = 0; i < 4; i++)
#pragma unroll
        for (int j = 0; j < 4; j++)
            sc[i][j] = __builtin_amdgcn_mfma_f32_16x16x32_bf16(
                qf[i], kf[j], sc[i][j], 0, 0, 0);

    // stage V^T: [d][tok], zero-pad toks 49..63 (P there is exactly 0)
    for (int e = lane; e < NTOK * 128; e += 64) {
        int tok = e >> 7, d = e & 127;
        sVt[d * 72 + tok] = qkv[(base + tok) * HQKV + head * 192 + 64 + d];
    }
    for (int t = lane; t < 128 * 15; t += 64) {
        int d = t / 15, tok = NTOK + t % 15;
        sVt[d * 72 + tok] = 0;
    }

    // softmax over (j regs x 16 lanes) per output row; P -> sP as bf16
#pragma unroll
    for (int i = 0; i < 4; i++)
#pragma unroll
        for (int r = 0; r < 4; r++) {
            float s0 = sc[i][0][r] * QK_SCALE;
            float s1 = sc[i][1][r] * QK_SCALE;
            float s2 = sc[i][2][r] * QK_SCALE;
            float s3 = sc[i][3][r] * QK_SCALE;
            float m = fmaxf(fmaxf(s0, s1), fmaxf(s2, s3));
#pragma unroll
            for (int o = 1; o < 16; o <<= 1) m = fmaxf(m, __shfl_xor(m, o, 64));
            float e0 = __expf(s0 - m), e1 = __expf(s1 - m);
            float e2 = __expf(s2 - m), e3 = __expf(s3 - m);
            float l = e0 + e1 + e2 + e3;
#pragma unroll
            for (int o = 1; o < 16; o <<= 1) l += __shfl_xor(l, o, 64);
            float inv = 1.0f / l;
            short* pr = &sP[(i * 16 + lq * 4 + r) * 72];
            pr[lr]      = f2b(e0 * inv);
            pr[16 + lr] = f2b(e1 * inv);
            pr[32 + lr] = f2b(e2 * inv);
            pr[48 + lr] = f2b(e3 * inv);
        }
    __syncthreads();

    // PV: A = P (rows=query, k=token), B = V^T rows (n=d, k=token); 2 d-halves
    bf16x8 pa[4][2];
#pragma unroll
    for (int i = 0; i < 4; i++)
#pragma unroll
        for (int kk = 0; kk < 2; kk++)
            pa[i][kk] = *(const bf16x8*)&sP[(i * 16 + lr) * 72 + kk * 32 + lq * 8];

#pragma unroll
    for (int half = 0; half < 2; half++) {
        const f32x4 fz = {0.f, 0.f, 0.f, 0.f};
        f32x4 o[4][4];
        bf16x8 pb[4][2];
#pragma unroll
        for (int j = 0; j < 4; j++)
#pragma unroll
            for (int kk = 0; kk < 2; kk++)
                pb[j][kk] = *(const bf16x8*)
                    &sVt[(half * 64 + j * 16 + lr) * 72 + kk * 32 + lq * 8];
#pragma unroll
        for (int i = 0; i < 4; i++)
#pragma unroll
            for (int j = 0; j < 4; j++) {
                o[i][j] = __builtin_amdgcn_mfma_f32_16x16x32_bf16(
                    pa[i][0], pb[j][0], fz, 0, 0, 0);
                o[i][j] = __builtin_amdgcn_mfma_f32_16x16x32_bf16(
                    pa[i][1], pb[j][1], o[i][j], 0, 0, 0);
            }
#pragma unroll
        for (int i = 0; i < 4; i++)
#pragma unroll
            for (int j = 0; j < 4; j++)
#pragma unroll
                for (int r = 0; r < 4; r++) {
                    int row = i * 16 + lq * 4 + r;
                    if (row < NTOK)
                        attn_out[(base + row) * DHID + head * 128 + half * 64 + j * 16 + lr] =
                            f2b(o[i][j][r]);
                }
    }
}

extern "C" void kernel_launch(void* const* d_in, const int* in_sizes, int n_in,
                              void* d_out, int out_size, void* d_ws, size_t ws_size,
                              hipStream_t stream) {
    const float* x      = (const float*)d_in[0];
    const float* qkv_w  = (const float*)d_in[1];
    const float* qkv_b  = (const float*)d_in[2];
    const float* proj_w = (const float*)d_in[3];
    const float* proj_b = (const float*)d_in[4];
    const float* fc1_w  = (const float*)d_in[5];
    const float* fc1_b  = (const float*)d_in[6];
    const float* fc2_w  = (const float*)d_in[7];
    const float* fc2_b  = (const float*)d_in[8];
    const float* n1g    = (const float*)d_in[9];
    const float* n1b    = (const float*)d_in[10];
    const float* n2g    = (const float*)d_in[11];
    const float* n2b    = (const float*)d_in[12];
    const float* ls1    = (const float*)d_in[13];
    const float* ls2    = (const float*)d_in[14];
    const float* biases = (const float*)d_in[15];
    const int*   bidx   = (const int*)d_in[16];
    float* outp = (float*)d_out;

    char* ws = (char*)d_ws;
    short* Wq = (short*)ws; ws += (size_t)688128 * 2;
    short* Wp = (short*)ws; ws += (size_t)458752 * 2;
    short* W1 = (short*)ws; ws += (size_t)802816 * 2;
    short* W2 = (short*)ws; ws += (size_t)802816 * 2;
    float* bfull = (float*)ws; ws += (size_t)NHEAD * NTOK * NTOK * 4;
    const size_t fixed = 5505024 + (size_t)NHEAD * NTOK * NTOK * 4;

    int IC = 1024;
    while (IC > 128) {
        size_t Rr = (size_t)IC * NTOK;
        if (fixed + Rr * 7808ull <= ws_size) break;
        IC >>= 1;
    }
    const size_t R = (size_t)IC * NTOK;
    short* hbuf = (short*)ws; ws += R * CDIM * 2;   // LN out (reused LN2)
    float* x1   = (float*)ws; ws += R * CDIM * 4;   // post-attn residual fp32
    short* qkvb = (short*)ws; ws += R * HQKV * 2;
    short* attb = (short*)ws; ws += R * DHID * 2;
    short* gbuf = qkvb;  // FC1 out [R,1792] overlays qkv+attn (dead by then)

    convert_w<<<3136, 256, 0, stream>>>(qkv_w, proj_w, fc1_w, fc2_w, Wq, Wp, W1, W2);
    build_bias<<<(NHEAD * NTOK * NTOK + 255) / 256, 256, 0, stream>>>(biases, bidx, bfull);

    for (int c0 = 0; c0 < 1024; c0 += IC) {
        const float* xc = x + (size_t)c0 * NTOK * CDIM;
        float* oc = outp + (size_t)c0 * NTOK * CDIM;
        const int Ri = IC * NTOK;

        ln_kernel<<<Ri / 4, 256, 0, stream>>>(xc, hbuf, n1g, n1b);
        gemm_bt<0><<<dim3(HQKV / 128, Ri / 128), 256, 0, stream>>>(
            hbuf, Wq, qkv_b, nullptr, nullptr, nullptr, qkvb, Ri, HQKV, CDIM);
        attn_mfma<<<dim3(NHEAD, IC), 64, 0, stream>>>(qkvb, bfull, attb);
        gemm_bt<2><<<dim3(4, Ri / 128), 256, 0, stream>>>(
            attb, Wp, proj_b, ls1, xc, x1, nullptr, Ri, CDIM, DHID);
        ln_kernel<<<Ri / 4, 256, 0, stream>>>(x1, hbuf, n2g, n2b);
        gemm_bt<1><<<dim3(FHID / 128, Ri / 128), 256, 0, stream>>>(
            hbuf, W1, fc1_b, nullptr, nullptr, nullptr, gbuf, Ri, FHID, CDIM);
        gemm_bt<2><<<dim3(4, Ri / 128), 256, 0, stream>>>(
            gbuf, W2, fc2_b, ls2, x1, oc, nullptr, Ri, CDIM, FHID);
    }
}